// Round 1
// baseline (730.629 us; speedup 1.0000x reference)
//
#include <hip/hip_runtime.h>
#include <hip/hip_bf16.h>

#define NUM_RATINGS 10
#define D 64

// ---------------- sort-by-rating scratch layout in d_ws ----------------
// [0..15]   int cnt[16]
// [16..31]  int offsets[16]
// [32..47]  int cursor[16]
// [64.. ]   int list[E]

__global__ void k_zero(int* __restrict__ cnt) {
    if (threadIdx.x < 16) cnt[threadIdx.x] = 0;
}

// block-aggregated histogram: 256 threads x 4 edges/thread
__global__ void k_hist(const int* __restrict__ rating, int n, int* __restrict__ cnt) {
    __shared__ int h[NUM_RATINGS];
    if (threadIdx.x < NUM_RATINGS) h[threadIdx.x] = 0;
    __syncthreads();
    int b0 = blockIdx.x * (blockDim.x * 4) + threadIdx.x;
    #pragma unroll
    for (int i = 0; i < 4; ++i) {
        int e = b0 + i * blockDim.x;
        if (e < n) atomicAdd(&h[rating[e]], 1);
    }
    __syncthreads();
    if (threadIdx.x < NUM_RATINGS) atomicAdd(&cnt[threadIdx.x], h[threadIdx.x]);
}

__global__ void k_prefix(const int* __restrict__ cnt, int* __restrict__ offsets,
                         int* __restrict__ cursor) {
    if (threadIdx.x == 0 && blockIdx.x == 0) {
        int s = 0;
        for (int r = 0; r < NUM_RATINGS; ++r) {
            offsets[r] = s; cursor[r] = s; s += cnt[r];
        }
        offsets[NUM_RATINGS] = s;
    }
}

// block-aggregated scatter into rating-sorted list
__global__ void k_scatter(const int* __restrict__ rating, int n,
                          int* __restrict__ cursor, int* __restrict__ list) {
    __shared__ int h[NUM_RATINGS];
    __shared__ int base[NUM_RATINGS];
    if (threadIdx.x < NUM_RATINGS) h[threadIdx.x] = 0;
    __syncthreads();
    int rk[4], rr[4], ee[4];
    int b0 = blockIdx.x * (blockDim.x * 4) + threadIdx.x;
    #pragma unroll
    for (int i = 0; i < 4; ++i) {
        int e = b0 + i * blockDim.x;
        ee[i] = e;
        if (e < n) {
            int r = rating[e];
            rr[i] = r;
            rk[i] = atomicAdd(&h[r], 1);
        }
    }
    __syncthreads();
    if (threadIdx.x < NUM_RATINGS)
        base[threadIdx.x] = atomicAdd(&cursor[threadIdx.x], h[threadIdx.x]);
    __syncthreads();
    #pragma unroll
    for (int i = 0; i < 4; ++i)
        if (ee[i] < n) list[base[rr[i]] + rk[i]] = ee[i];
}

// ---------------- main compute ----------------
// One wave per contiguous chunk of the rating-sorted edge list.
// Lane j computes output element j. W row j (64 f32) held in registers,
// reloaded only when the (wave-uniform) rating changes.
__global__ __launch_bounds__(256) void k_main(
    const float* __restrict__ embed, const float* __restrict__ weights,
    const float* __restrict__ invc, const int* __restrict__ enode,
    const int* __restrict__ erating, const int* __restrict__ list,
    float* __restrict__ out, int n, int chunk) {

    int wv = __builtin_amdgcn_readfirstlane((int)(threadIdx.x >> 6));
    int lane = threadIdx.x & 63;
    long start = ((long)blockIdx.x * 4 + wv) * (long)chunk;
    long end = start + chunk;
    if (end > n) end = n;

    int cur_r = -1;
    float w[D];

    for (long p = start; p < end; ++p) {
        int e = list[p];          // wave-uniform address -> uniform value
        int r = erating[e];       // uniform
        if (r != cur_r) {
            cur_r = r;
            const float4* wp = reinterpret_cast<const float4*>(
                weights + (size_t)r * (D * D) + (size_t)lane * D);
            #pragma unroll
            for (int q = 0; q < D / 4; ++q) {
                float4 t = wp[q];
                w[q * 4 + 0] = t.x; w[q * 4 + 1] = t.y;
                w[q * 4 + 2] = t.z; w[q * 4 + 3] = t.w;
            }
        }
        int node = enode[e];      // uniform
        const float4* xp = reinterpret_cast<const float4*>(embed + (size_t)node * D);
        float a0 = 0.f, a1 = 0.f, a2 = 0.f, a3 = 0.f;
        #pragma unroll
        for (int q = 0; q < D / 4; ++q) {
            float4 x = xp[q];     // uniform address -> single coalesced request
            a0 = fmaf(x.x, w[q * 4 + 0], a0);
            a1 = fmaf(x.y, w[q * 4 + 1], a1);
            a2 = fmaf(x.z, w[q * 4 + 2], a2);
            a3 = fmaf(x.w, w[q * 4 + 3], a3);
        }
        float res = ((a0 + a1) + (a2 + a3)) * invc[e];
        out[(size_t)node * D + lane] = res;
    }
}

extern "C" void kernel_launch(void* const* d_in, const int* in_sizes, int n_in,
                              void* d_out, int out_size, void* d_ws, size_t ws_size,
                              hipStream_t stream) {
    const float* embed   = (const float*)d_in[0];
    const float* weights = (const float*)d_in[1];
    const float* invc    = (const float*)d_in[2];
    const int*   enode   = (const int*)d_in[3];
    const int*   erating = (const int*)d_in[4];
    float* out = (float*)d_out;

    int E = in_sizes[3];   // number of edges

    int* ws_i    = (int*)d_ws;
    int* cnt     = ws_i + 0;
    int* offsets = ws_i + 16;
    int* cursor  = ws_i + 32;
    int* list    = ws_i + 64;

    // 1) zero counters
    hipLaunchKernelGGL(k_zero, dim3(1), dim3(64), 0, stream, cnt);

    // 2) histogram (256 thr x 4 edges)
    int hb = (E + 1023) / 1024;
    hipLaunchKernelGGL(k_hist, dim3(hb), dim3(256), 0, stream, erating, E, cnt);

    // 3) prefix sums
    hipLaunchKernelGGL(k_prefix, dim3(1), dim3(64), 0, stream, cnt, offsets, cursor);

    // 4) scatter into sorted list
    hipLaunchKernelGGL(k_scatter, dim3(hb), dim3(256), 0, stream, erating, E, cursor, list);

    // 5) main compute: 2048 blocks x 4 waves, contiguous chunks
    const int totalWaves = 8192;
    int chunk = (E + totalWaves - 1) / totalWaves;
    hipLaunchKernelGGL(k_main, dim3(totalWaves / 4), dim3(256), 0, stream,
                       embed, weights, invc, enode, erating, list, out, E, chunk);
}

// Round 2
// 353.243 us; speedup vs baseline: 2.0683x; 2.0683x over previous
//
#include <hip/hip_runtime.h>
#include <hip/hip_bf16.h>

#define NUM_RATINGS 10
#define D 64

// ---------------- d_ws layout ----------------
// [0..15]   int cnt[16]
// [16..31]  int offsets[16]   (offsets[0..10] used; offsets[10] == E)
// [32..47]  int cursor[16]
// [64.. ]   int2 meta[E]      (node, inv_c bits), rating-sorted

__global__ void k_zero(int* __restrict__ cnt) {
    if (threadIdx.x < 16) cnt[threadIdx.x] = 0;
}

__global__ void k_hist(const int* __restrict__ rating, int n, int* __restrict__ cnt) {
    __shared__ int h[NUM_RATINGS];
    if (threadIdx.x < NUM_RATINGS) h[threadIdx.x] = 0;
    __syncthreads();
    int b0 = blockIdx.x * (blockDim.x * 4) + threadIdx.x;
    #pragma unroll
    for (int i = 0; i < 4; ++i) {
        int e = b0 + i * blockDim.x;
        if (e < n) atomicAdd(&h[rating[e]], 1);
    }
    __syncthreads();
    if (threadIdx.x < NUM_RATINGS) atomicAdd(&cnt[threadIdx.x], h[threadIdx.x]);
}

__global__ void k_prefix(const int* __restrict__ cnt, int* __restrict__ offsets,
                         int* __restrict__ cursor) {
    if (threadIdx.x == 0 && blockIdx.x == 0) {
        int s = 0;
        for (int r = 0; r < NUM_RATINGS; ++r) {
            offsets[r] = s; cursor[r] = s; s += cnt[r];
        }
        offsets[NUM_RATINGS] = s;
    }
}

// scatter edges into rating-sorted meta array: (node, inv_c bits)
__global__ void k_scatter(const int* __restrict__ rating, const int* __restrict__ enode,
                          const float* __restrict__ invc, int n,
                          int* __restrict__ cursor, int2* __restrict__ meta) {
    __shared__ int h[NUM_RATINGS];
    __shared__ int base[NUM_RATINGS];
    if (threadIdx.x < NUM_RATINGS) h[threadIdx.x] = 0;
    __syncthreads();
    int rk[4], rr[4], ee[4];
    int b0 = blockIdx.x * (blockDim.x * 4) + threadIdx.x;
    #pragma unroll
    for (int i = 0; i < 4; ++i) {
        int e = b0 + i * blockDim.x;
        ee[i] = e;
        if (e < n) {
            int r = rating[e];
            rr[i] = r;
            rk[i] = atomicAdd(&h[r], 1);
        }
    }
    __syncthreads();
    if (threadIdx.x < NUM_RATINGS)
        base[threadIdx.x] = atomicAdd(&cursor[threadIdx.x], h[threadIdx.x]);
    __syncthreads();
    #pragma unroll
    for (int i = 0; i < 4; ++i)
        if (ee[i] < n)
            meta[base[rr[i]] + rk[i]] = make_int2(enode[ee[i]], __float_as_int(invc[ee[i]]));
}

// ---------------- main compute ----------------
// Lane j owns output element j; W[r] row j lives in 16 named float4 regs.
// x row loaded with ONE coalesced global_load_dword (lane k holds x[k]);
// x[k] broadcast via v_readlane (constant lane, unrolled).
// Software pipeline: meta ring 8-deep (named), x ring 4-deep (named), unroll-8.

#define RL(x, k) __uint_as_float(__builtin_amdgcn_readlane(__float_as_uint(x), (k)))

#define LOADW(r) { \
    const float4* wp_ = reinterpret_cast<const float4*>( \
        weights + ((size_t)(r) << 12) + ((size_t)lane << 6)); \
    w0 = wp_[0];  w1 = wp_[1];  w2 = wp_[2];  w3 = wp_[3]; \
    w4 = wp_[4];  w5 = wp_[5];  w6 = wp_[6];  w7 = wp_[7]; \
    w8 = wp_[8];  w9 = wp_[9];  w10 = wp_[10]; w11 = wp_[11]; \
    w12 = wp_[12]; w13 = wp_[13]; w14 = wp_[14]; w15 = wp_[15]; }

#define K4(xi, q) \
    a0 = fmaf(RL(xi, 4*(q)+0), w##q.x, a0); \
    a1 = fmaf(RL(xi, 4*(q)+1), w##q.y, a1); \
    a2 = fmaf(RL(xi, 4*(q)+2), w##q.z, a2); \
    a3 = fmaf(RL(xi, 4*(q)+3), w##q.w, a3);

#define DOT64(xi) \
    K4(xi, 0)  K4(xi, 1)  K4(xi, 2)  K4(xi, 3) \
    K4(xi, 4)  K4(xi, 5)  K4(xi, 6)  K4(xi, 7) \
    K4(xi, 8)  K4(xi, 9)  K4(xi, 10) K4(xi, 11) \
    K4(xi, 12) K4(xi, 13) K4(xi, 14) K4(xi, 15)

// I  : step index 0..7 (edge q = p + I)
// XS : x ring slot   = I & 3
// MS : meta ring slot = I
// M4 : meta slot for edge q+4 = (I+4) & 7
#define STEP(I, XS, MS, M4) { \
    int q = p + (I); \
    if (q >= boundary) { \
        do { ++r; boundary = offs[r + 1]; } while (q >= boundary); \
        LOADW(r); \
    } \
    float a0 = 0.f, a1 = 0.f, a2 = 0.f, a3 = 0.f; \
    DOT64(xv##XS) \
    float res = ((a0 + a1) + (a2 + a3)) * __int_as_float(m##MS.y); \
    if (q < end) out[((size_t)m##MS.x << 6) + lane] = res; \
    int qm = q + 8;  if (qm > Em1) qm = Em1; \
    m##MS = meta[qm]; \
    xv##XS = embed[((size_t)m##M4.x << 6) + lane]; \
}

__global__ __launch_bounds__(256) void k_main(
    const float* __restrict__ embed, const float* __restrict__ weights,
    const int* __restrict__ offs, const int2* __restrict__ meta,
    float* __restrict__ out, int E, int chunk) {

    int wv = __builtin_amdgcn_readfirstlane((int)(threadIdx.x >> 6));
    int lane = threadIdx.x & 63;
    int start = (blockIdx.x * 4 + wv) * chunk;       // chunk % 8 == 0
    if (start >= E) return;
    int end = start + chunk; if (end > E) end = E;
    int Em1 = E - 1;

    // rating bucket for the chunk start
    int r = 0;
    int boundary = offs[1];
    while (start >= boundary) { ++r; boundary = offs[r + 1]; }

    float4 w0, w1, w2, w3, w4, w5, w6, w7, w8, w9, w10, w11, w12, w13, w14, w15;
    LOADW(r);

    // meta prologue (edges start .. start+7 -> slots 0..7 since start%8==0)
    int2 m0, m1, m2, m3, m4, m5, m6, m7;
    {
        int q;
        q = start + 0; if (q > Em1) q = Em1; m0 = meta[q];
        q = start + 1; if (q > Em1) q = Em1; m1 = meta[q];
        q = start + 2; if (q > Em1) q = Em1; m2 = meta[q];
        q = start + 3; if (q > Em1) q = Em1; m3 = meta[q];
        q = start + 4; if (q > Em1) q = Em1; m4 = meta[q];
        q = start + 5; if (q > Em1) q = Em1; m5 = meta[q];
        q = start + 6; if (q > Em1) q = Em1; m6 = meta[q];
        q = start + 7; if (q > Em1) q = Em1; m7 = meta[q];
    }
    // x prologue (edges start .. start+3 -> x slots 0..3)
    float xv0 = embed[((size_t)m0.x << 6) + lane];
    float xv1 = embed[((size_t)m1.x << 6) + lane];
    float xv2 = embed[((size_t)m2.x << 6) + lane];
    float xv3 = embed[((size_t)m3.x << 6) + lane];

    for (int p = start; p < end; p += 8) {
        STEP(0, 0, 0, 4)
        STEP(1, 1, 1, 5)
        STEP(2, 2, 2, 6)
        STEP(3, 3, 3, 7)
        STEP(4, 0, 4, 0)
        STEP(5, 1, 5, 1)
        STEP(6, 2, 6, 2)
        STEP(7, 3, 7, 3)
    }
}

extern "C" void kernel_launch(void* const* d_in, const int* in_sizes, int n_in,
                              void* d_out, int out_size, void* d_ws, size_t ws_size,
                              hipStream_t stream) {
    const float* embed   = (const float*)d_in[0];
    const float* weights = (const float*)d_in[1];
    const float* invc    = (const float*)d_in[2];
    const int*   enode   = (const int*)d_in[3];
    const int*   erating = (const int*)d_in[4];
    float* out = (float*)d_out;

    int E = in_sizes[3];

    int*  ws_i    = (int*)d_ws;
    int*  cnt     = ws_i + 0;
    int*  offsets = ws_i + 16;
    int*  cursor  = ws_i + 32;
    int2* meta    = (int2*)(ws_i + 64);

    hipLaunchKernelGGL(k_zero, dim3(1), dim3(64), 0, stream, cnt);

    int hb = (E + 1023) / 1024;
    hipLaunchKernelGGL(k_hist, dim3(hb), dim3(256), 0, stream, erating, E, cnt);
    hipLaunchKernelGGL(k_prefix, dim3(1), dim3(64), 0, stream, cnt, offsets, cursor);
    hipLaunchKernelGGL(k_scatter, dim3(hb), dim3(256), 0, stream,
                       erating, enode, invc, E, cursor, meta);

    // 4096 waves (1024 blocks x 4 waves), chunk multiple of 8
    const int totalWaves = 4096;
    int chunk = (E + totalWaves - 1) / totalWaves;
    chunk = (chunk + 7) & ~7;
    hipLaunchKernelGGL(k_main, dim3(totalWaves / 4), dim3(256), 0, stream,
                       embed, weights, offsets, meta, out, E, chunk);
}

// Round 4
// 170.813 us; speedup vs baseline: 4.2774x; 2.0680x over previous
//
#include <hip/hip_runtime.h>
#include <hip/hip_bf16.h>

#define NUM_RATINGS 10
#define CH 4   // tiles per wave

typedef short bf16x8 __attribute__((ext_vector_type(8)));
typedef float f32x4 __attribute__((ext_vector_type(4)));

// ---------------- d_ws layout (ints) ----------------
// [0..15]   cnt[16]
// [16..31]  poff[16]   padded offsets (multiples of 16); poff[10] = padded total
// [32..47]  cursor[16]
// [48..63]  rend[16]   real end of bucket r = poff[r] + cnt[r]
// [64.. ]   int2 meta[E]   (node, inv_c bits), rating-sorted, NO pad entries

__global__ void k_zero(int* __restrict__ cnt) {
    if (threadIdx.x < 16) cnt[threadIdx.x] = 0;
}

__global__ void k_hist(const int* __restrict__ rating, int n, int* __restrict__ cnt) {
    __shared__ int h[NUM_RATINGS];
    if (threadIdx.x < NUM_RATINGS) h[threadIdx.x] = 0;
    __syncthreads();
    int b0 = blockIdx.x * (blockDim.x * 4) + threadIdx.x;
    #pragma unroll
    for (int i = 0; i < 4; ++i) {
        int e = b0 + i * blockDim.x;
        if (e < n) atomicAdd(&h[rating[e]], 1);
    }
    __syncthreads();
    if (threadIdx.x < NUM_RATINGS) atomicAdd(&cnt[threadIdx.x], h[threadIdx.x]);
}

// padded prefix offsets + real-end markers; NO meta writes (ws-overflow-safe)
__global__ void k_prefix(const int* __restrict__ cnt, int* __restrict__ poff,
                         int* __restrict__ cursor, int* __restrict__ rend) {
    if (threadIdx.x == 0 && blockIdx.x == 0) {
        int s = 0;
        for (int r = 0; r < NUM_RATINGS; ++r) {
            poff[r] = s; cursor[r] = s;
            rend[r] = s + cnt[r];
            s += (cnt[r] + 15) & ~15;
        }
        poff[NUM_RATINGS] = s;
    }
}

// scatter edges into rating-sorted meta: (node, inv_c bits). Real entries only.
__global__ void k_scatter(const int* __restrict__ rating, const int* __restrict__ enode,
                          const float* __restrict__ invc, int n,
                          int* __restrict__ cursor, int2* __restrict__ meta) {
    __shared__ int h[NUM_RATINGS];
    __shared__ int base[NUM_RATINGS];
    if (threadIdx.x < NUM_RATINGS) h[threadIdx.x] = 0;
    __syncthreads();
    int rk[4], rr[4], ee[4];
    int b0 = blockIdx.x * (blockDim.x * 4) + threadIdx.x;
    #pragma unroll
    for (int i = 0; i < 4; ++i) {
        int e = b0 + i * blockDim.x;
        ee[i] = e;
        if (e < n) {
            int r = rating[e];
            rr[i] = r;
            rk[i] = atomicAdd(&h[r], 1);
        }
    }
    __syncthreads();
    if (threadIdx.x < NUM_RATINGS)
        base[threadIdx.x] = atomicAdd(&cursor[threadIdx.x], h[threadIdx.x]);
    __syncthreads();
    #pragma unroll
    for (int i = 0; i < 4; ++i)
        if (ee[i] < n)
            meta[base[rr[i]] + rk[i]] = make_int2(enode[ee[i]], __float_as_int(invc[ee[i]]));
}

// ---- RNE f32 -> bf16 packing helpers (static indexing only) ----
static __device__ __forceinline__ bf16x8 rne8(float4 a, float4 b) {
    float f[8] = {a.x, a.y, a.z, a.w, b.x, b.y, b.z, b.w};
    union { unsigned short us[8]; bf16x8 v; } U;
    #pragma unroll
    for (int i = 0; i < 8; ++i) {
        unsigned u = __float_as_uint(f[i]);
        U.us[i] = (unsigned short)((u + 0x7fffu + ((u >> 16) & 1u)) >> 16);
    }
    return U.v;
}

static __device__ __forceinline__ bf16x8 rne8s(float4 a, float4 b, float s) {
    float f[8] = {a.x, a.y, a.z, a.w, b.x, b.y, b.z, b.w};
    union { unsigned short us[8]; bf16x8 v; } U;
    #pragma unroll
    for (int i = 0; i < 8; ++i) {
        unsigned u = __float_as_uint(f[i] * s);
        U.us[i] = (unsigned short)((u + 0x7fffu + ((u >> 16) & 1u)) >> 16);
    }
    return U.v;
}

// B-fragment: lane l holds W[16*t_ + (l&15)][32*ks_ + 8*(l>>4) + i], i=0..7
#define LOADW(rr) { \
    const float* wr_ = weights + ((size_t)(rr) << 12); \
    _Pragma("unroll") \
    for (int t_ = 0; t_ < 4; ++t_) { \
        _Pragma("unroll") \
        for (int ks_ = 0; ks_ < 2; ++ks_) { \
            const float4* p_ = reinterpret_cast<const float4*>( \
                wr_ + (16 * t_ + eh) * 64 + 32 * ks_ + 8 * kg); \
            B[t_][ks_] = rne8(p_[0], p_[1]); \
        } \
    } }

// One wave = CH consecutive 16-edge tiles. Lane: eh = l&15 (edge slot / out col),
// kg = l>>4 (k-octet group). A: lane holds x[edge eh][8kg..8kg+7] (and +32).
// D (m89): row(edge) = 4*kg + reg, col(out) = eh.
__global__ __launch_bounds__(256) void k_main(
    const float* __restrict__ embed, const float* __restrict__ weights,
    const int* __restrict__ poff, const int* __restrict__ rend,
    const int2* __restrict__ meta, float* __restrict__ out) {

    int lane = threadIdx.x & 63;
    int wv = threadIdx.x >> 6;
    int eh = lane & 15;
    int kg = lane >> 4;

    int Tp = poff[NUM_RATINGS] >> 4;
    int t_base = (blockIdx.x * 4 + wv) * CH;
    if (t_base >= Tp) return;

    // cache bucket offsets (uniform)
    int pf[NUM_RATINGS];
    #pragma unroll
    for (int q = 0; q < NUM_RATINGS; ++q) pf[q] = poff[q];

    int cur_r = -1;
    bf16x8 B[4][2];

    #pragma unroll
    for (int it = 0; it < CH; ++it) {
        int t = t_base + it;
        if (t >= Tp) break;
        int tslot = t << 4;

        // bucket of this tile (tiles never straddle buckets: poff multiples of 16)
        int r = 0;
        #pragma unroll
        for (int q = 1; q < NUM_RATINGS; ++q) r += (tslot >= pf[q]) ? 1 : 0;
        if (r != cur_r) { cur_r = r; LOADW(r); }

        int slot = tslot + eh;
        bool valid = slot < rend[r];
        int2 m = meta[valid ? slot : 0];
        int nd = valid ? m.x : 0;
        float s = valid ? __int_as_float(m.y) : 0.f;

        const float4* xp = reinterpret_cast<const float4*>(embed + ((size_t)nd << 6));
        float4 x0 = xp[2 * kg], x1 = xp[2 * kg + 1];
        float4 x2 = xp[8 + 2 * kg], x3 = xp[9 + 2 * kg];

        bf16x8 a0 = rne8s(x0, x1, s);   // k = 8kg..8kg+7
        bf16x8 a1 = rne8s(x2, x3, s);   // k = 32+8kg..+7

        f32x4 acc[4];
        #pragma unroll
        for (int tt = 0; tt < 4; ++tt) acc[tt] = (f32x4){0.f, 0.f, 0.f, 0.f};
        #pragma unroll
        for (int tt = 0; tt < 4; ++tt)
            acc[tt] = __builtin_amdgcn_mfma_f32_16x16x32_bf16(a0, B[tt][0], acc[tt], 0, 0, 0);
        #pragma unroll
        for (int tt = 0; tt < 4; ++tt)
            acc[tt] = __builtin_amdgcn_mfma_f32_16x16x32_bf16(a1, B[tt][1], acc[tt], 0, 0, 0);

        // store: lane holds D[4kg+rg][16tt+eh]; node of edge 4kg+rg via shfl
        int vnd = valid ? m.x : -1;
        int kg4 = kg << 2;
        #pragma unroll
        for (int rg = 0; rg < 4; ++rg) {
            int nd2 = __shfl(vnd, kg4 + rg, 64);
            if (nd2 >= 0) {
                float* po = out + ((size_t)nd2 << 6) + eh;
                po[0]  = acc[0][rg];
                po[16] = acc[1][rg];
                po[32] = acc[2][rg];
                po[48] = acc[3][rg];
            }
        }
    }
}

extern "C" void kernel_launch(void* const* d_in, const int* in_sizes, int n_in,
                              void* d_out, int out_size, void* d_ws, size_t ws_size,
                              hipStream_t stream) {
    const float* embed   = (const float*)d_in[0];
    const float* weights = (const float*)d_in[1];
    const float* invc    = (const float*)d_in[2];
    const int*   enode   = (const int*)d_in[3];
    const int*   erating = (const int*)d_in[4];
    float* out = (float*)d_out;

    int E = in_sizes[3];

    int*  ws_i   = (int*)d_ws;
    int*  cnt    = ws_i + 0;
    int*  poff   = ws_i + 16;
    int*  cursor = ws_i + 32;
    int*  rend   = ws_i + 48;
    int2* meta   = (int2*)(ws_i + 64);

    hipLaunchKernelGGL(k_zero, dim3(1), dim3(64), 0, stream, cnt);

    int hb = (E + 1023) / 1024;
    hipLaunchKernelGGL(k_hist, dim3(hb), dim3(256), 0, stream, erating, E, cnt);
    hipLaunchKernelGGL(k_prefix, dim3(1), dim3(64), 0, stream, cnt, poff, cursor, rend);
    hipLaunchKernelGGL(k_scatter, dim3(hb), dim3(256), 0, stream,
                       erating, enode, invc, E, cursor, meta);

    // upper bound on padded tile count; device reads exact Tp from poff[10]
    int Tp_up = (E + 15 * NUM_RATINGS + 15) / 16;
    int waves = (Tp_up + CH - 1) / CH;
    int blocks = (waves + 3) / 4;
    hipLaunchKernelGGL(k_main, dim3(blocks), dim3(256), 0, stream,
                       embed, weights, poff, rend, meta, out);
}

// Round 5
// 155.088 us; speedup vs baseline: 4.7111x; 1.1014x over previous
//
#include <hip/hip_runtime.h>
#include <hip/hip_bf16.h>

#define NUM_RATINGS 10
#define CH 8   // tiles per wave

typedef short bf16x8 __attribute__((ext_vector_type(8)));
typedef float f32x4 __attribute__((ext_vector_type(4)));

// ---------------- d_ws layout (ints) ----------------
// [0..15]   cnt[16]
// [16..31]  poff[16]   padded offsets (multiples of 16); poff[10] = padded total
// [32..47]  cursor[16]
// [48..63]  rend[16]   real end of bucket r = poff[r] + cnt[r]
// [64.. ]   int2 meta[E]   (node, inv_c bits), rating-sorted, NO pad entries

__global__ void k_zero(int* __restrict__ cnt) {
    if (threadIdx.x < 16) cnt[threadIdx.x] = 0;
}

__global__ void k_hist(const int* __restrict__ rating, int n, int* __restrict__ cnt) {
    __shared__ int h[NUM_RATINGS];
    if (threadIdx.x < NUM_RATINGS) h[threadIdx.x] = 0;
    __syncthreads();
    int b0 = blockIdx.x * (blockDim.x * 4) + threadIdx.x;
    #pragma unroll
    for (int i = 0; i < 4; ++i) {
        int e = b0 + i * blockDim.x;
        if (e < n) atomicAdd(&h[rating[e]], 1);
    }
    __syncthreads();
    if (threadIdx.x < NUM_RATINGS) atomicAdd(&cnt[threadIdx.x], h[threadIdx.x]);
}

__global__ void k_prefix(const int* __restrict__ cnt, int* __restrict__ poff,
                         int* __restrict__ cursor, int* __restrict__ rend) {
    if (threadIdx.x == 0 && blockIdx.x == 0) {
        int s = 0;
        for (int r = 0; r < NUM_RATINGS; ++r) {
            poff[r] = s; cursor[r] = s;
            rend[r] = s + cnt[r];
            s += (cnt[r] + 15) & ~15;
        }
        poff[NUM_RATINGS] = s;
    }
}

__global__ void k_scatter(const int* __restrict__ rating, const int* __restrict__ enode,
                          const float* __restrict__ invc, int n,
                          int* __restrict__ cursor, int2* __restrict__ meta) {
    __shared__ int h[NUM_RATINGS];
    __shared__ int base[NUM_RATINGS];
    if (threadIdx.x < NUM_RATINGS) h[threadIdx.x] = 0;
    __syncthreads();
    int rk[4], rr[4], ee[4];
    int b0 = blockIdx.x * (blockDim.x * 4) + threadIdx.x;
    #pragma unroll
    for (int i = 0; i < 4; ++i) {
        int e = b0 + i * blockDim.x;
        ee[i] = e;
        if (e < n) {
            int r = rating[e];
            rr[i] = r;
            rk[i] = atomicAdd(&h[r], 1);
        }
    }
    __syncthreads();
    if (threadIdx.x < NUM_RATINGS)
        base[threadIdx.x] = atomicAdd(&cursor[threadIdx.x], h[threadIdx.x]);
    __syncthreads();
    #pragma unroll
    for (int i = 0; i < 4; ++i)
        if (ee[i] < n)
            meta[base[rr[i]] + rk[i]] = make_int2(enode[ee[i]], __float_as_int(invc[ee[i]]));
}

// ---- RNE f32 -> bf16 packing (static indexing only) ----
static __device__ __forceinline__ bf16x8 rne8(float4 a, float4 b) {
    float f[8] = {a.x, a.y, a.z, a.w, b.x, b.y, b.z, b.w};
    union { unsigned short us[8]; bf16x8 v; } U;
    #pragma unroll
    for (int i = 0; i < 8; ++i) {
        unsigned u = __float_as_uint(f[i]);
        U.us[i] = (unsigned short)((u + 0x7fffu + ((u >> 16) & 1u)) >> 16);
    }
    return U.v;
}

static __device__ __forceinline__ bf16x8 rne8s(float4 a, float4 b, float s) {
    float f[8] = {a.x, a.y, a.z, a.w, b.x, b.y, b.z, b.w};
    union { unsigned short us[8]; bf16x8 v; } U;
    #pragma unroll
    for (int i = 0; i < 8; ++i) {
        unsigned u = __float_as_uint(f[i] * s);
        U.us[i] = (unsigned short)((u + 0x7fffu + ((u >> 16) & 1u)) >> 16);
    }
    return U.v;
}

// B-fragment: lane l holds W[16*t_ + (l&15)][32*ks_ + 8*(l>>4) + i], i=0..7
#define LOADW(rr) { \
    const float* wr_ = weights + ((size_t)(rr) << 12); \
    _Pragma("unroll") \
    for (int t_ = 0; t_ < 4; ++t_) { \
        _Pragma("unroll") \
        for (int ks_ = 0; ks_ < 2; ++ks_) { \
            const float4* p_ = reinterpret_cast<const float4*>( \
                wr_ + (16 * t_ + eh) * 64 + 32 * ks_ + 8 * kg); \
            B[t_][ks_] = rne8(p_[0], p_[1]); \
        } \
    } }

// uniform bucket + real-end select chain (named scalars, no runtime indexing)
#define BUCKET(tslot, rr, rv) { \
    rr = 0; rv = re0; \
    if ((tslot) >= pf1) { rr = 1; rv = re1; } \
    if ((tslot) >= pf2) { rr = 2; rv = re2; } \
    if ((tslot) >= pf3) { rr = 3; rv = re3; } \
    if ((tslot) >= pf4) { rr = 4; rv = re4; } \
    if ((tslot) >= pf5) { rr = 5; rv = re5; } \
    if ((tslot) >= pf6) { rr = 6; rv = re6; } \
    if ((tslot) >= pf7) { rr = 7; rv = re7; } \
    if ((tslot) >= pf8) { rr = 8; rv = re8; } \
    if ((tslot) >= pf9) { rr = 9; rv = re9; } }

// load embed row fragment for tile I into x slot S (S is A or B token)
#define XLOAD(S, I) { \
    int nd_ = V[I] ? M[I].x : 0; \
    const float4* xp_ = reinterpret_cast<const float4*>(embed + ((size_t)nd_ << 6)); \
    x##S##0 = xp_[2 * kg];     x##S##1 = xp_[2 * kg + 1]; \
    x##S##2 = xp_[8 + 2 * kg]; x##S##3 = xp_[9 + 2 * kg]; }

// compute tile I from slot S, then reuse slot S for tile IP2 (= I+2, padded)
#define STEP(I, IP2, S) { \
    if (R[I] != cur_r) { cur_r = R[I]; LOADW(cur_r); } \
    float s_ = V[I] ? __int_as_float(M[I].y) : 0.f; \
    bf16x8 a0_ = rne8s(x##S##0, x##S##1, s_); \
    bf16x8 a1_ = rne8s(x##S##2, x##S##3, s_); \
    XLOAD(S, IP2) \
    f32x4 acc[4]; \
    _Pragma("unroll") \
    for (int tt = 0; tt < 4; ++tt) acc[tt] = (f32x4){0.f, 0.f, 0.f, 0.f}; \
    _Pragma("unroll") \
    for (int tt = 0; tt < 4; ++tt) \
        acc[tt] = __builtin_amdgcn_mfma_f32_16x16x32_bf16(a0_, B[tt][0], acc[tt], 0, 0, 0); \
    _Pragma("unroll") \
    for (int tt = 0; tt < 4; ++tt) \
        acc[tt] = __builtin_amdgcn_mfma_f32_16x16x32_bf16(a1_, B[tt][1], acc[tt], 0, 0, 0); \
    int vnd_ = V[I] ? M[I].x : -1; \
    int kg4_ = kg << 2; \
    _Pragma("unroll") \
    for (int rg = 0; rg < 4; ++rg) { \
        int nd2_ = __shfl(vnd_, kg4_ + rg, 64); \
        if (nd2_ >= 0) { \
            float* po_ = out + ((size_t)nd2_ << 6) + eh; \
            __builtin_nontemporal_store(acc[0][rg], po_); \
            __builtin_nontemporal_store(acc[1][rg], po_ + 16); \
            __builtin_nontemporal_store(acc[2][rg], po_ + 32); \
            __builtin_nontemporal_store(acc[3][rg], po_ + 48); \
        } \
    } }

__global__ __launch_bounds__(256) void k_main(
    const float* __restrict__ embed, const float* __restrict__ weights,
    const int* __restrict__ poff, const int* __restrict__ rend,
    const int2* __restrict__ meta, float* __restrict__ out) {

    int lane = threadIdx.x & 63;
    int wv = threadIdx.x >> 6;
    int eh = lane & 15;
    int kg = lane >> 4;

    int Tp = poff[NUM_RATINGS] >> 4;
    int t_base = (blockIdx.x * 4 + wv) * CH;
    if (t_base >= Tp) return;

    // uniform scalar caches
    int pf1 = poff[1], pf2 = poff[2], pf3 = poff[3], pf4 = poff[4], pf5 = poff[5];
    int pf6 = poff[6], pf7 = poff[7], pf8 = poff[8], pf9 = poff[9];
    int re0 = rend[0], re1 = rend[1], re2 = rend[2], re3 = rend[3], re4 = rend[4];
    int re5 = rend[5], re6 = rend[6], re7 = rend[7], re8 = rend[8], re9 = rend[9];

    // issue all CH meta loads upfront (independent)
    int2 M[CH + 2];
    int  R[CH];
    bool V[CH + 2];
    #pragma unroll
    for (int i = 0; i < CH; ++i) {
        int t = t_base + i;
        int tslot = t << 4;
        int r_, rv_;
        BUCKET(tslot, r_, rv_);
        R[i] = r_;
        int slot = tslot + eh;
        bool valid = (t < Tp) && (slot < rv_);
        V[i] = valid;
        M[i] = meta[valid ? slot : 0];
    }
    M[CH] = M[CH - 1];     V[CH] = false;
    M[CH + 1] = M[CH - 1]; V[CH + 1] = false;

    bf16x8 B[4][2];
    int cur_r = R[0];
    LOADW(cur_r);

    // x pipeline prologue: slots A,B hold tiles 0,1
    float4 xA0, xA1, xA2, xA3, xB0, xB1, xB2, xB3;
    XLOAD(A, 0)
    XLOAD(B, 1)

    STEP(0, 2, A)
    STEP(1, 3, B)
    STEP(2, 4, A)
    STEP(3, 5, B)
    STEP(4, 6, A)
    STEP(5, 7, B)
    STEP(6, 8, A)
    STEP(7, 9, B)
}

extern "C" void kernel_launch(void* const* d_in, const int* in_sizes, int n_in,
                              void* d_out, int out_size, void* d_ws, size_t ws_size,
                              hipStream_t stream) {
    const float* embed   = (const float*)d_in[0];
    const float* weights = (const float*)d_in[1];
    const float* invc    = (const float*)d_in[2];
    const int*   enode   = (const int*)d_in[3];
    const int*   erating = (const int*)d_in[4];
    float* out = (float*)d_out;

    int E = in_sizes[3];

    int*  ws_i   = (int*)d_ws;
    int*  cnt    = ws_i + 0;
    int*  poff   = ws_i + 16;
    int*  cursor = ws_i + 32;
    int*  rend   = ws_i + 48;
    int2* meta   = (int2*)(ws_i + 64);

    hipLaunchKernelGGL(k_zero, dim3(1), dim3(64), 0, stream, cnt);

    int hb = (E + 1023) / 1024;
    hipLaunchKernelGGL(k_hist, dim3(hb), dim3(256), 0, stream, erating, E, cnt);
    hipLaunchKernelGGL(k_prefix, dim3(1), dim3(64), 0, stream, cnt, poff, cursor, rend);
    hipLaunchKernelGGL(k_scatter, dim3(hb), dim3(256), 0, stream,
                       erating, enode, invc, E, cursor, meta);

    // upper bound on padded tile count; device reads exact Tp from poff[10]
    int Tp_up = (E + 15 * NUM_RATINGS + 15) / 16;
    int waves = (Tp_up + CH - 1) / CH;
    int blocks = (waves + 3) / 4;
    hipLaunchKernelGGL(k_main, dim3(blocks), dim3(256), 0, stream,
                       embed, weights, poff, rend, meta, out);
}

// Round 6
// 129.303 us; speedup vs baseline: 5.6505x; 1.1994x over previous
//
#include <hip/hip_runtime.h>
#include <hip/hip_bf16.h>

#define NUM_RATINGS 10

typedef short bf16x8 __attribute__((ext_vector_type(8)));
typedef float f32x4 __attribute__((ext_vector_type(4)));

// ---- RNE f32 -> bf16 packing (static indexing only) ----
static __device__ __forceinline__ bf16x8 rne8(float4 a, float4 b) {
    float f[8] = {a.x, a.y, a.z, a.w, b.x, b.y, b.z, b.w};
    union { unsigned short us[8]; bf16x8 v; } U;
    #pragma unroll
    for (int i = 0; i < 8; ++i) {
        unsigned u = __float_as_uint(f[i]);
        U.us[i] = (unsigned short)((u + 0x7fffu + ((u >> 16) & 1u)) >> 16);
    }
    return U.v;
}

// ---------------- W -> bf16 B-fragment precompute ----------------
// Layout: wf[(r*8 + j)*64 + lane], j = tt*2 + ks.
// Lane l (eh=l&15, kg=l>>4) holds W[r][16*tt + eh][32*ks + 8*kg + i], i=0..7.
__global__ void k_wfrag(const float* __restrict__ w, bf16x8* __restrict__ wf) {
    int r = blockIdx.x;
    int lane = threadIdx.x & 63;
    int eh = lane & 15, kg = lane >> 4;
    #pragma unroll
    for (int j = 0; j < 8; ++j) {
        int tt = j >> 1, ks = j & 1;
        const float4* p = reinterpret_cast<const float4*>(
            w + ((size_t)r << 12) + (size_t)(16 * tt + eh) * 64 + 32 * ks + 8 * kg);
        wf[(r * 8 + j) * 64 + lane] = rne8(p[0], p[1]);
    }
}

// ---------------- main compute ----------------
// Natural edge order: one wave = 64 consecutive edges (4 MFMA tiles of 16).
// With the actual data (enode = arange) every embed read and out write is
// hardware-coalesced (16 consecutive 256B rows per tile). Mixed ratings are
// handled by masked MFMA accumulation over all 10 ratings; inv_c applied to
// the f32 accumulator at store time. D (m89): row(edge)=4*kg+rg, col=16*tt+eh.
__global__ __launch_bounds__(256) void k_main(
    const float* __restrict__ embed, const bf16x8* __restrict__ wf,
    const float* __restrict__ invc, const int* __restrict__ enode,
    const int* __restrict__ erating, float* __restrict__ out, int E) {

    int lane = threadIdx.x & 63;
    int wv = threadIdx.x >> 6;
    int eh = lane & 15, kg = lane >> 4;
    int e0 = (blockIdx.x * 4 + wv) * 64;
    if (e0 >= E) return;

    // per-tile metadata (lane eh <-> edge e0+16*it+eh), clamped at tail
    int nd[4]; int rt[4]; float sc[4];
    #pragma unroll
    for (int it = 0; it < 4; ++it) {
        int et = e0 + 16 * it + eh;
        if (et > E - 1) et = E - 1;
        nd[it] = enode[et];
        rt[it] = erating[et];
        sc[it] = invc[et];
    }

    // A-fragments, unscaled: lane holds x[edge eh][8kg..8kg+7] and [32+8kg..]
    bf16x8 a0[4], a1[4];
    #pragma unroll
    for (int it = 0; it < 4; ++it) {
        const float4* xp = reinterpret_cast<const float4*>(embed + ((size_t)nd[it] << 6));
        float4 x0 = xp[2 * kg],     x1 = xp[2 * kg + 1];
        float4 x2 = xp[8 + 2 * kg], x3 = xp[9 + 2 * kg];
        a0[it] = rne8(x0, x1);
        a1[it] = rne8(x2, x3);
    }

    f32x4 acc[4][4];
    #pragma unroll
    for (int it = 0; it < 4; ++it)
        #pragma unroll
        for (int tt = 0; tt < 4; ++tt) acc[it][tt] = (f32x4){0.f, 0.f, 0.f, 0.f};

    // masked accumulation over ratings; unroll 1 keeps B live-range at 32 VGPR
    #pragma unroll 1
    for (int r = 0; r < NUM_RATINGS; ++r) {
        bf16x8 B[8];
        #pragma unroll
        for (int j = 0; j < 8; ++j) B[j] = wf[(r * 8 + j) * 64 + lane];
        #pragma unroll
        for (int it = 0; it < 4; ++it) {
            bool m = (rt[it] == r);
            bf16x8 z = (bf16x8)(short)0;
            bf16x8 am0 = m ? a0[it] : z;
            bf16x8 am1 = m ? a1[it] : z;
            #pragma unroll
            for (int tt = 0; tt < 4; ++tt) {
                acc[it][tt] = __builtin_amdgcn_mfma_f32_16x16x32_bf16(am0, B[2 * tt],     acc[it][tt], 0, 0, 0);
                acc[it][tt] = __builtin_amdgcn_mfma_f32_16x16x32_bf16(am1, B[2 * tt + 1], acc[it][tt], 0, 0, 0);
            }
        }
    }

    // store: lane holds D[4kg+rg][16tt+eh]; node/scale of edge 4kg+rg via shfl
    int kg4 = kg << 2;
    #pragma unroll
    for (int it = 0; it < 4; ++it) {
        #pragma unroll
        for (int rg = 0; rg < 4; ++rg) {
            int er = e0 + 16 * it + kg4 + rg;
            int nd2 = __shfl(nd[it], kg4 + rg, 64);
            float s2 = __shfl(sc[it], kg4 + rg, 64);
            if (er < E) {
                float* po = out + ((size_t)nd2 << 6) + eh;
                __builtin_nontemporal_store(acc[it][0][rg] * s2, po);
                __builtin_nontemporal_store(acc[it][1][rg] * s2, po + 16);
                __builtin_nontemporal_store(acc[it][2][rg] * s2, po + 32);
                __builtin_nontemporal_store(acc[it][3][rg] * s2, po + 48);
            }
        }
    }
}

extern "C" void kernel_launch(void* const* d_in, const int* in_sizes, int n_in,
                              void* d_out, int out_size, void* d_ws, size_t ws_size,
                              hipStream_t stream) {
    const float* embed   = (const float*)d_in[0];
    const float* weights = (const float*)d_in[1];
    const float* invc    = (const float*)d_in[2];
    const int*   enode   = (const int*)d_in[3];
    const int*   erating = (const int*)d_in[4];
    float* out = (float*)d_out;

    int E = in_sizes[3];

    bf16x8* wf = (bf16x8*)d_ws;   // 10 * 8 * 64 * 16B = 80 KiB

    hipLaunchKernelGGL(k_wfrag, dim3(NUM_RATINGS), dim3(64), 0, stream, weights, wf);

    int waves = (E + 63) / 64;
    int blocks = (waves + 3) / 4;
    hipLaunchKernelGGL(k_main, dim3(blocks), dim3(256), 0, stream,
                       embed, wf, invc, enode, erating, out, E);
}